// Round 1
// baseline (516.758 us; speedup 1.0000x reference)
//
#include <hip/hip_runtime.h>
#include <hip/hip_bf16.h>

// Problem constants
#define B_DIM   512
#define IN_DIM  4096
#define OUT_DIM 11008

typedef __bf16 bf16x4 __attribute__((ext_vector_type(4)));
typedef __bf16 bf16x8 __attribute__((ext_vector_type(8)));
typedef float  floatx4 __attribute__((ext_vector_type(4)));

// ---------------------------------------------------------------------------
// Pass 1: x fp32 -> bf16 (tiny: 12 MB traffic, ~2 us)
// ---------------------------------------------------------------------------
__global__ __launch_bounds__(256) void conv_x_kernel(
    const float* __restrict__ x, __bf16* __restrict__ xb) {
  int idx = blockIdx.x * blockDim.x + threadIdx.x;  // quad index
  float4 v = ((const float4*)x)[idx];
  bf16x4 o;
  o[0] = (__bf16)v.x; o[1] = (__bf16)v.y; o[2] = (__bf16)v.z; o[3] = (__bf16)v.w;
  ((bf16x4*)xb)[idx] = o;
}

// ---------------------------------------------------------------------------
// Pass 2: fused QINS-decode + GEMM.
// C = A(512x4096) * W^T, W decoded on the fly from stored/sign int32.
// 128x128 tile, BK=32, 256 threads = 4 waves in 2x2, mfma_f32_16x16x32_bf16.
// A staged via global_load_lds (double-buffered sA); B staged via
// global->reg int4 loads, in-register decode to bf16, ds_write_b128 to sB.
// Raw s_barrier + one manual vmcnt(0) per tile => next-tile A & B loads stay
// in flight across the MFMA section (software pipeline, no full drain).
// Epilogue: out = acc*scale + bias*scale (fp32).
// ---------------------------------------------------------------------------
__device__ __forceinline__ void gl_lds16(const __bf16* g, __bf16* l) {
  __builtin_amdgcn_global_load_lds(
      (const __attribute__((address_space(1))) void*)g,
      (__attribute__((address_space(3))) void*)l, 16, 0, 0);
}

// Raw workgroup barrier with compiler memory fences (no vmcnt drain).
__device__ __forceinline__ void memfence_barrier() {
  asm volatile("" ::: "memory");
  __builtin_amdgcn_s_barrier();
  asm volatile("" ::: "memory");
}

// Decode one QINS element: w = sign * exp(lmin + (255 - s)/254 * (lmax-lmin))
// (numerics identical to the previously-passing decode_w_kernel)
__device__ __forceinline__ __bf16 dec1(int s, int g, float lmin, float slope) {
  return (__bf16)(__expf(lmin + (float)(255 - s) * slope) * (float)g);
}

__global__ __launch_bounds__(256, 2) void fused_qins_gemm_kernel(
    const __bf16* __restrict__ A,      // 512 x 4096 bf16 (pre-converted x)
    const int* __restrict__ stored,    // 11008 x 4096 int32 in [1,255]
    const int* __restrict__ sign,      // 11008 x 4096 int32 +-1
    const float* __restrict__ logmin, const float* __restrict__ logmax,
    const float* __restrict__ scale, const float* __restrict__ bias,
    float* __restrict__ out) {
  constexpr int K = IN_DIM, N = OUT_DIM;
  constexpr int BK = 32;

  __shared__ __align__(16) __bf16 sA[2 * 128 * BK];  // 16 KB (double buffer)
  __shared__ __align__(16) __bf16 sB[128 * BK];      // 8 KB

  const int tid  = threadIdx.x;
  const int lane = tid & 63;
  const int wave = tid >> 6;
  const int wm   = (wave >> 1) * 64;   // wave row offset in tile
  const int wn   = (wave & 1) * 64;    // wave col offset in tile
  const int m16  = lane & 15;
  const int q    = lane >> 4;          // quad 0..3

  // XCD-grouped swizzle: 344 blocks = 8 XCDs x 43. bm varies fastest within
  // a group so the 4 blocks sharing a bn panel land on the SAME XCD ->
  // stored/sign panel (4 MB) reuse hits that XCD's L2, HBM reads W once.
  const int wg  = blockIdx.x;                 // 0..343
  const int g   = (wg & 7) * 43 + (wg >> 3);  // bijective (344 = 8*43)
  const int bn0 = (g >> 2) * 128;             // 86 N-tiles
  const int bm0 = (g & 3) * 128;              // 4 M-tiles

  const float lmin  = logmin[0];
  const float slope = (logmax[0] - lmin) * (1.0f / 254.0f);

  // A staging (global_load_lds, lane-ordered row-major [128][32] layout)
  const int r0 = tid >> 2;
  const int c0 = (tid & 3) * 8;
  const __bf16* gA0 = A + (bm0 + r0) * K + c0;
  const __bf16* gA1 = A + (bm0 + r0 + 64) * K + c0;

  // B staging: thread -> (row rB = tid>>1, k-half kh) ; 16 elems/thread/tile.
  // Threads t,t+1 cover one row's full 128 B k-window -> cacheline-covered.
  const int rB = tid >> 1;
  const int kh = (tid & 1) * 16;
  const int* pS = stored + (size_t)(bn0 + rB) * K + kh;
  const int* pG = sign   + (size_t)(bn0 + rB) * K + kh;
  __bf16* lB = sB + rB * BK + kh;

  floatx4 acc[4][4] = {};

  // Prologue: A(0) -> sA buf0 (async), B(0) -> regs.
  gl_lds16(gA0, sA + tid * 8);
  gl_lds16(gA1, sA + 2048 + tid * 8);
  int4 s0 = ((const int4*)pS)[0], s1 = ((const int4*)pS)[1],
       s2 = ((const int4*)pS)[2], s3 = ((const int4*)pS)[3];
  int4 g0 = ((const int4*)pG)[0], g1 = ((const int4*)pG)[1],
       g2 = ((const int4*)pG)[2], g3 = ((const int4*)pG)[3];

  for (int kt = 0; kt < K; kt += BK) {
    const int cur = (kt >> 5) & 1;
    __bf16* sAc = sA + cur * 4096;         // buffer holding A(kt)
    __bf16* sAn = sA + (cur ^ 1) * 4096;   // buffer for A(kt+BK)

    // Decode tile kt from regs prefetched one iteration ago (VALU only).
    bf16x8 w0, w1;
    w0[0] = dec1(s0.x, g0.x, lmin, slope);
    w0[1] = dec1(s0.y, g0.y, lmin, slope);
    w0[2] = dec1(s0.z, g0.z, lmin, slope);
    w0[3] = dec1(s0.w, g0.w, lmin, slope);
    w0[4] = dec1(s1.x, g1.x, lmin, slope);
    w0[5] = dec1(s1.y, g1.y, lmin, slope);
    w0[6] = dec1(s1.z, g1.z, lmin, slope);
    w0[7] = dec1(s1.w, g1.w, lmin, slope);
    w1[0] = dec1(s2.x, g2.x, lmin, slope);
    w1[1] = dec1(s2.y, g2.y, lmin, slope);
    w1[2] = dec1(s2.z, g2.z, lmin, slope);
    w1[3] = dec1(s2.w, g2.w, lmin, slope);
    w1[4] = dec1(s3.x, g3.x, lmin, slope);
    w1[5] = dec1(s3.y, g3.y, lmin, slope);
    w1[6] = dec1(s3.z, g3.z, lmin, slope);
    w1[7] = dec1(s3.w, g3.w, lmin, slope);

    // B1: all waves have consumed previous tile's sB / sA[cur^1] fragments
    // (ds_reads retired before their MFMAs issued, which precede this point).
    memfence_barrier();

    *(bf16x8*)lB       = w0;
    *(bf16x8*)(lB + 8) = w1;

    // A(kt) was issued one tile ago -> near-zero stall here in steady state.
    // Also makes this wave's ds_writes visible for post-barrier readers.
    asm volatile("s_waitcnt vmcnt(0) lgkmcnt(0)" ::: "memory");

    // Issue next tile's loads AFTER the drain so they stay in flight across
    // the MFMA section (hidden latency), BEFORE B2 (buffer sAn is free:
    // everyone passed B1, so its last readers are done).
    if (kt + BK < K) {
      gl_lds16(gA0 + kt + BK, sAn + tid * 8);
      gl_lds16(gA1 + kt + BK, sAn + 2048 + tid * 8);
      const int4* nS = (const int4*)(pS + kt + BK);
      const int4* nG = (const int4*)(pG + kt + BK);
      s0 = nS[0]; s1 = nS[1]; s2 = nS[2]; s3 = nS[3];
      g0 = nG[0]; g1 = nG[1]; g2 = nG[2]; g3 = nG[3];
    }

    // B2: sA[cur] + sB now fully populated for every wave.
    memfence_barrier();

    bf16x8 afr[4], bfr[4];
#pragma unroll
    for (int i = 0; i < 4; ++i)
      afr[i] = *(const bf16x8*)&sAc[(wm + i * 16 + m16) * BK + q * 8];
#pragma unroll
    for (int i = 0; i < 4; ++i)
      bfr[i] = *(const bf16x8*)&sB[(wn + i * 16 + m16) * BK + q * 8];

#pragma unroll
    for (int mi = 0; mi < 4; ++mi)
#pragma unroll
      for (int ni = 0; ni < 4; ++ni)
        acc[mi][ni] = __builtin_amdgcn_mfma_f32_16x16x32_bf16(
            afr[mi], bfr[ni], acc[mi][ni], 0, 0, 0);
  }

  // Epilogue. C/D layout: col = lane&15, row = q*4 + reg  [m89]
#pragma unroll
  for (int ni = 0; ni < 4; ++ni) {
    const int col = bn0 + wn + ni * 16 + m16;
    const float sc = scale[col];
    const float bb = bias[col] * sc;
#pragma unroll
    for (int mi = 0; mi < 4; ++mi) {
#pragma unroll
      for (int r = 0; r < 4; ++r) {
        const int row = bm0 + wm + mi * 16 + q * 4 + r;
        out[row * N + col] = acc[mi][ni][r] * sc + bb;
      }
    }
  }
}

// ---------------------------------------------------------------------------
extern "C" void kernel_launch(void* const* d_in, const int* in_sizes, int n_in,
                              void* d_out, int out_size, void* d_ws, size_t ws_size,
                              hipStream_t stream) {
  const float* x      = (const float*)d_in[0];
  const int*   stored = (const int*)d_in[1];
  const int*   sign   = (const int*)d_in[2];
  const float* logmin = (const float*)d_in[3];
  const float* logmax = (const float*)d_in[4];
  const float* scale  = (const float*)d_in[5];
  const float* bias   = (const float*)d_in[6];
  float* out = (float*)d_out;

  __bf16* wsX = (__bf16*)d_ws;  // 512*4096 bf16 = 4 MB

  // convert x: 2,097,152 elems / 4 / 256 = 2048 blocks
  conv_x_kernel<<<2048, 256, 0, stream>>>(x, wsX);
  // fused decode+GEMM: 86 N-tiles x 4 M-tiles = 344 blocks (XCD-swizzled)
  fused_qins_gemm_kernel<<<344, 256, 0, stream>>>(
      wsX, stored, sign, logmin, logmax, scale, bias, out);
}

// Round 2
// 461.940 us; speedup vs baseline: 1.1187x; 1.1187x over previous
//
#include <hip/hip_runtime.h>
#include <hip/hip_bf16.h>

// Problem constants
#define B_DIM   512
#define IN_DIM  4096
#define OUT_DIM 11008

typedef __bf16 bf16x4 __attribute__((ext_vector_type(4)));
typedef __bf16 bf16x8 __attribute__((ext_vector_type(8)));
typedef float  floatx4 __attribute__((ext_vector_type(4)));

// ---------------------------------------------------------------------------
// Pass 1: x fp32 -> bf16 (tiny: 12 MB traffic, ~2 us)
// ---------------------------------------------------------------------------
__global__ __launch_bounds__(256) void conv_x_kernel(
    const float* __restrict__ x, __bf16* __restrict__ xb) {
  int idx = blockIdx.x * blockDim.x + threadIdx.x;  // quad index
  float4 v = ((const float4*)x)[idx];
  bf16x4 o;
  o[0] = (__bf16)v.x; o[1] = (__bf16)v.y; o[2] = (__bf16)v.z; o[3] = (__bf16)v.w;
  ((bf16x4*)xb)[idx] = o;
}

// ---------------------------------------------------------------------------
// Pass 2: fused QINS-decode + GEMM, v2.
// Changes vs v1 (265 us, 14.8% occ, 8.45M LDS conflicts):
//  - BM=128 x BN=64 tiles -> 688 blocks (2.7 blk/CU, tail 1.12x not 1.49x)
//  - sB padded to stride 40 elems (80 B): ds_write/ds_read <=2-way (free)
//  - sA XOR k-slot swizzle via pre-swizzled GLOBAL source (m173): 8->4-way
//  - 2-deep B register prefetch, uniform counted s_waitcnt vmcnt(4) per tile
//    (B(i+2) stays in flight across the whole tile; never a full drain)
// ---------------------------------------------------------------------------
__device__ __forceinline__ void gl_lds16(const __bf16* g, __bf16* l) {
  __builtin_amdgcn_global_load_lds(
      (const __attribute__((address_space(1))) void*)g,
      (__attribute__((address_space(3))) void*)l, 16, 0, 0);
}

__device__ __forceinline__ void memfence_barrier() {
  asm volatile("" ::: "memory");
  __builtin_amdgcn_s_barrier();
  asm volatile("" ::: "memory");
}

// w = sign * exp(lmin + (255 - s)/254 * (lmax-lmin))  (numerics as v1, passed)
__device__ __forceinline__ __bf16 dec1(int s, int g, float lmin, float slope) {
  return (__bf16)(__expf(lmin + (float)(255 - s) * slope) * (float)g);
}

__device__ __forceinline__ bf16x8 dec8(int4 sl, int4 sh, int4 gl, int4 gh,
                                       float lmin, float slope) {
  bf16x8 w;
  w[0] = dec1(sl.x, gl.x, lmin, slope);
  w[1] = dec1(sl.y, gl.y, lmin, slope);
  w[2] = dec1(sl.z, gl.z, lmin, slope);
  w[3] = dec1(sl.w, gl.w, lmin, slope);
  w[4] = dec1(sh.x, gh.x, lmin, slope);
  w[5] = dec1(sh.y, gh.y, lmin, slope);
  w[6] = dec1(sh.z, gh.z, lmin, slope);
  w[7] = dec1(sh.w, gh.w, lmin, slope);
  return w;
}

__global__ __launch_bounds__(256, 2) void fused_qins_gemm_kernel(
    const __bf16* __restrict__ A,      // 512 x 4096 bf16 (pre-converted x)
    const int* __restrict__ stored,    // 11008 x 4096 int32 in [1,255]
    const int* __restrict__ sign,      // 11008 x 4096 int32 +-1
    const float* __restrict__ logmin, const float* __restrict__ logmax,
    const float* __restrict__ scale, const float* __restrict__ bias,
    float* __restrict__ out) {
  constexpr int K = IN_DIM, N = OUT_DIM;
  constexpr int BK = 32;
  constexpr int NIT = K / BK;          // 128 k-tiles
  constexpr int SBS = 40;              // sB padded row stride (elems, 80 B)

  __shared__ __align__(16) __bf16 sA[2][128 * BK];  // 2 x 8 KB
  __shared__ __align__(16) __bf16 sB[64 * SBS];     // 5 KB

  const int tid  = threadIdx.x;
  const int lane = tid & 63;
  const int wave = tid >> 6;
  const int wm   = (wave >> 1) * 64;   // wave M offset (0/64)
  const int wn   = (wave & 1) * 32;    // wave N offset (0/32)
  const int m16  = lane & 15;
  const int q    = lane >> 4;          // 0..3

  // XCD-grouped swizzle: 688 = 8 XCDs x 86; bm fastest so the 4 blocks
  // sharing a bn panel co-reside on one XCD (stored/sign reuse hits L2).
  const int wg  = blockIdx.x;                 // 0..687
  const int g   = (wg & 7) * 86 + (wg >> 3);  // bijective
  const int bm0 = (g & 3) * 128;              // 4 M-tiles
  const int bn0 = (g >> 2) * 64;              // 172 N-tiles

  const float lmin  = logmin[0];
  const float slope = (logmax[0] - lmin) * (1.0f / 254.0f);

  // ---- A staging: global_load_lds, 2 chunks, pre-swizzled k-slot (XOR) ----
  const int rA   = tid >> 2;                   // 0..63
  const int slot = (tid & 3) ^ (rA & 3);       // k-slot XOR pre-swizzle
  const __bf16* gA0 = A + (bm0 + rA) * K + slot * 8;        // (rA+64)&3==rA&3
  const __bf16* gA1 = A + (bm0 + rA + 64) * K + slot * 8;
  const int aReadSlot = q ^ (m16 & 3);         // read-side inverse of XOR

  // ---- B staging: global int4 -> regs -> decode -> padded sB ----
  const int rB = tid >> 2;                     // 0..63
  const int kq = (tid & 3) * 8;                // k elem offset 0/8/16/24
  const int* pS = stored + (size_t)(bn0 + rB) * K + kq;
  const int* pG = sign   + (size_t)(bn0 + rB) * K + kq;
  __bf16* lB = sB + rB * SBS + kq;             // byte 80*rB+16*(tid&3): aligned

  floatx4 acc[4][2] = {};

  // Prologue: B(0) -> set0, B(1) -> set1, A(0) -> sA[0]
  int4 s0a = ((const int4*)pS)[0], s1a = ((const int4*)pS)[1];
  int4 g0a = ((const int4*)pG)[0], g1a = ((const int4*)pG)[1];
  int4 s0b = ((const int4*)(pS + BK))[0], s1b = ((const int4*)(pS + BK))[1];
  int4 g0b = ((const int4*)(pG + BK))[0], g1b = ((const int4*)(pG + BK))[1];
  gl_lds16(gA0, sA[0] + tid * 8);
  gl_lds16(gA1, sA[0] + 2048 + tid * 8);

  // Per-iter i (steady state), issue order guarantees outstanding vmem at the
  // counted wait = {B(i+1):4, A(i):2, B(i+2):4} -> vmcnt(4) completes A(i)
  // (and B(i+1)) while B(i+2) stays in flight. Tail iters clamp prefetch
  // addresses to kt=0 (dead loads) so the count stays uniform.
#define BODY(i, S0, S1, G0, G1, CUR, NXT)                                     \
  {                                                                           \
    bf16x8 w = dec8(S0, S1, G0, G1, lmin, slope);                             \
    const int kt2 = ((i) + 2 < NIT) ? ((i) + 2) * BK : 0;                     \
    S0 = ((const int4*)(pS + kt2))[0]; S1 = ((const int4*)(pS + kt2))[1];     \
    G0 = ((const int4*)(pG + kt2))[0]; G1 = ((const int4*)(pG + kt2))[1];     \
    memfence_barrier();                  /* prev readers of sB/sA[NXT] done */ \
    *(bf16x8*)lB = w;                                                         \
    asm volatile("s_waitcnt vmcnt(4) lgkmcnt(0)" ::: "memory");               \
    const int kt1 = ((i) + 1 < NIT) ? ((i) + 1) * BK : 0;                     \
    gl_lds16(gA0 + kt1, (NXT) + tid * 8);                                     \
    gl_lds16(gA1 + kt1, (NXT) + 2048 + tid * 8);                              \
    memfence_barrier();                  /* sA[CUR] + sB ready everywhere */  \
    bf16x8 afr[4], bfr[2];                                                    \
    _Pragma("unroll")                                                         \
    for (int ii = 0; ii < 4; ++ii)                                            \
      afr[ii] = *(const bf16x8*)&(CUR)[(wm + ii * 16 + m16) * BK +            \
                                       aReadSlot * 8];                        \
    _Pragma("unroll")                                                         \
    for (int ii = 0; ii < 2; ++ii)                                            \
      bfr[ii] = *(const bf16x8*)&sB[(wn + ii * 16 + m16) * SBS + q * 8];      \
    _Pragma("unroll")                                                         \
    for (int mi = 0; mi < 4; ++mi)                                            \
      _Pragma("unroll")                                                       \
      for (int ni = 0; ni < 2; ++ni)                                          \
        acc[mi][ni] = __builtin_amdgcn_mfma_f32_16x16x32_bf16(                \
            afr[mi], bfr[ni], acc[mi][ni], 0, 0, 0);                          \
  }

  for (int it = 0; it < NIT; it += 2) {
    BODY(it,     s0a, s1a, g0a, g1a, sA[0], sA[1]);
    BODY(it + 1, s0b, s1b, g0b, g1b, sA[1], sA[0]);
  }
#undef BODY

  // Epilogue. C/D layout: col = lane&15, row = q*4 + reg  [m89]
#pragma unroll
  for (int ni = 0; ni < 2; ++ni) {
    const int col = bn0 + wn + ni * 16 + m16;
    const float sc = scale[col];
    const float bb = bias[col] * sc;
#pragma unroll
    for (int mi = 0; mi < 4; ++mi) {
#pragma unroll
      for (int r = 0; r < 4; ++r) {
        const int row = bm0 + wm + mi * 16 + q * 4 + r;
        out[row * N + col] = acc[mi][ni][r] * sc + bb;
      }
    }
  }
}

// ---------------------------------------------------------------------------
extern "C" void kernel_launch(void* const* d_in, const int* in_sizes, int n_in,
                              void* d_out, int out_size, void* d_ws, size_t ws_size,
                              hipStream_t stream) {
  const float* x      = (const float*)d_in[0];
  const int*   stored = (const int*)d_in[1];
  const int*   sign   = (const int*)d_in[2];
  const float* logmin = (const float*)d_in[3];
  const float* logmax = (const float*)d_in[4];
  const float* scale  = (const float*)d_in[5];
  const float* bias   = (const float*)d_in[6];
  float* out = (float*)d_out;

  __bf16* wsX = (__bf16*)d_ws;  // 512*4096 bf16 = 4 MB

  conv_x_kernel<<<2048, 256, 0, stream>>>(x, wsX);
  // 172 bn-tiles x 4 bm-tiles = 688 blocks (XCD-swizzled)
  fused_qins_gemm_kernel<<<688, 256, 0, stream>>>(
      wsX, stored, sign, logmin, logmax, scale, bias, out);
}